// Round 4
// baseline (421.479 us; speedup 1.0000x reference)
//
#include <hip/hip_runtime.h>
#include <cstdint>

constexpr int B = 32, C = 256, H = 56, W = 56;
constexpr int HW = H * W;          // 3136
constexpr int WORDS = 8;           // 256 ci / 32
constexpr int TAPS = 9;
constexpr int WPC = TAPS * WORDS;  // 72
constexpr int PH = H + 2, PW = W + 2, PHW = PH * PW;  // 58x58

// ---------------------------------------------------------------------------
// Zero the pad ring of px (ws is re-poisoned to 0xAA before every launch).
// 228 ring pixels per image * 8 words * 32 images = 58368 threads exact.
// ---------------------------------------------------------------------------
__global__ __launch_bounds__(256) void pad_zero_kernel(uint32_t* __restrict__ px) {
    int idx = blockIdx.x * 256 + threadIdx.x;   // 228 blocks exact
    int wd = idx & 7;
    int r = idx >> 3;
    int ring = r % 228;
    int b = r / 228;
    int ph, pwp;
    if (ring < 58)       { ph = 0;              pwp = ring; }
    else if (ring < 116) { ph = 57;             pwp = ring - 58; }
    else if (ring < 172) { ph = 1 + (ring - 116); pwp = 0; }
    else                 { ph = 1 + (ring - 172); pwp = 57; }
    px[((size_t)(b * PH + ph) * PW + pwp) * WORDS + wd] = 0u;
}

// ---------------------------------------------------------------------------
// Pack x signs (interior only): thread = (b, wd, hw4); reads float4 (4 pixels)
// per channel plane, 32 planes -> 4 output words. Sign via MSB extraction.
// ---------------------------------------------------------------------------
__global__ __launch_bounds__(256) void pack_x_kernel(const float* __restrict__ x,
                                                     uint32_t* __restrict__ px) {
    int idx = blockIdx.x * 256 + threadIdx.x;   // 32*8*784 = 200704 exact
    int hw4 = idx % 784;
    int r = idx / 784;
    int wd = r & 7;
    int b = r >> 3;
    const float4* xp = reinterpret_cast<const float4*>(x + ((size_t)b * C + wd * 32) * HW) + hw4;
    uint32_t w0 = 0, w1 = 0, w2 = 0, w3 = 0;
    #pragma unroll
    for (int i = 0; i < 32; ++i) {
        float4 v = xp[(size_t)i * (HW / 4)];
        w0 |= (__float_as_uint(v.x) >> 31) << i;
        w1 |= (__float_as_uint(v.y) >> 31) << i;
        w2 |= (__float_as_uint(v.z) >> 31) << i;
        w3 |= (__float_as_uint(v.w) >> 31) << i;
    }
    int hw = hw4 * 4;
    #pragma unroll
    for (int q = 0; q < 4; ++q) {
        int h = (hw + q) / W, w = (hw + q) - h * W;
        uint32_t val = (q == 0) ? w0 : (q == 1) ? w1 : (q == 2) ? w2 : w3;
        px[((size_t)(b * PH + h + 1) * PW + (w + 1)) * WORDS + wd] = val;
    }
}

// ---------------------------------------------------------------------------
// Pack w signs via ballot: one wave per (co, tap, 64-ci chunk).
// pw[co][tap][wd], bit i of word wd = (w[co][wd*32+i][tap] < 0).
// ---------------------------------------------------------------------------
__global__ __launch_bounds__(256) void pack_w_kernel(const float* __restrict__ wt,
                                                     uint32_t* __restrict__ pw) {
    int gid = blockIdx.x * 256 + threadIdx.x;   // C*9*4*64 = 589824 exact
    int lane = gid & 63;
    int wv = gid >> 6;
    int pr = wv & 3;
    int ct = wv >> 2;
    int tap = ct % 9;
    int co = ct / 9;
    int ci = pr * 64 + lane;
    float v = wt[((size_t)co * C + ci) * TAPS + tap];
    unsigned long long m = __ballot(v < 0.0f);
    if (lane == 0) {
        pw[(size_t)co * WPC + tap * WORDS + pr * 2]     = (uint32_t)m;
        pw[(size_t)co * WPC + tap * WORDS + pr * 2 + 1] = (uint32_t)(m >> 32);
    }
}

// ---------------------------------------------------------------------------
// Main conv, lane = output channel. Block = 4 waves; wave wid covers
// co = wid*64+lane; all waves share the same 64-pixel hw chunk.
// Weights: 72 words in VGPRs, loaded ONCE. Per pixel p: the 3x3 px window is
// wave-uniform -> 3 rows x 24 contiguous words via the scalar pipe (K$,
// shared across the block's 4 waves). Border correction is wave-uniform,
// computed from per-tap weight popcounts tp[t] (pad words are zero):
//   out = 2304 + bias[co] + sum_{t invalid}(2*tp[t] - 256) - 2*popc_all.
// Stores: float4 per lane every 4 pixels into the lane's own co-row.
// ---------------------------------------------------------------------------
__global__ __launch_bounds__(256) void bconv_kernel(const uint32_t* __restrict__ px,
                                                    const uint32_t* __restrict__ pw,
                                                    const float* __restrict__ bias,
                                                    float* __restrict__ out) {
    const int lane = threadIdx.x & 63;
    const int wid = threadIdx.x >> 6;
    const int co = wid * 64 + lane;
    const int hwbase = blockIdx.x * 64;     // 49 blocks exact
    const int b = blockIdx.y;

    // ---- weights -> 72 VGPRs (one time) ----
    uint32_t wreg[WPC];
    {
        const uint4* wp = reinterpret_cast<const uint4*>(pw + (size_t)co * WPC);
        #pragma unroll
        for (int i = 0; i < 18; ++i) {
            uint4 v = wp[i];
            wreg[i * 4 + 0] = v.x; wreg[i * 4 + 1] = v.y;
            wreg[i * 4 + 2] = v.z; wreg[i * 4 + 3] = v.w;
        }
    }
    // per-tap weight popcounts (for border correction)
    uint32_t tp[TAPS];
    #pragma unroll
    for (int t = 0; t < TAPS; ++t) {
        uint32_t s = 0;
        #pragma unroll
        for (int k = 0; k < WORDS; ++k) s += __popc(wreg[t * WORDS + k]);
        tp[t] = s;
    }

    const float basep = 2304.0f + bias[co];
    float* outrow = out + ((size_t)b * C + co) * HW + hwbase;

    #pragma unroll 1
    for (int p4 = 0; p4 < 16; ++p4) {
        float o0, o1, o2, o3;
        #pragma unroll
        for (int q = 0; q < 4; ++q) {
            const int p = p4 * 4 + q;
            const int hw = hwbase + p;
            const int h = hw / W;          // wave-uniform
            const int w = hw - h * W;      // wave-uniform
            // padded top-left of the 3x3 window: row h (=h-1+1), col w
            const uint32_t* rp = px + ((size_t)(b * PH + h) * PW + w) * WORDS;
            uint32_t a0 = 0, a1 = 0, a2 = 0, a3 = 0;
            #pragma unroll
            for (int row = 0; row < 3; ++row) {
                const uint32_t* rr = rp + row * (PW * WORDS);  // 24 contiguous words
                #pragma unroll
                for (int c = 0; c < 3; ++c) {
                    const int t = row * 3 + c;
                    a0 += __popc(rr[c * 8 + 0] ^ wreg[t * 8 + 0]);
                    a1 += __popc(rr[c * 8 + 1] ^ wreg[t * 8 + 1]);
                    a2 += __popc(rr[c * 8 + 2] ^ wreg[t * 8 + 2]);
                    a3 += __popc(rr[c * 8 + 3] ^ wreg[t * 8 + 3]);
                    a0 += __popc(rr[c * 8 + 4] ^ wreg[t * 8 + 4]);
                    a1 += __popc(rr[c * 8 + 5] ^ wreg[t * 8 + 5]);
                    a2 += __popc(rr[c * 8 + 6] ^ wreg[t * 8 + 6]);
                    a3 += __popc(rr[c * 8 + 7] ^ wreg[t * 8 + 7]);
                }
            }
            const uint32_t total = (a0 + a1) + (a2 + a3);
            float base2 = basep;
            if (h == 0 || h == H - 1 || w == 0 || w == W - 1) {   // wave-uniform branch
                uint32_t s = 0;
                int ninv = 0;
                #pragma unroll
                for (int t = 0; t < TAPS; ++t) {
                    const int dh = t / 3, dw = t % 3;   // 0..2
                    const bool inv = (h == 0 && dh == 0) || (h == H - 1 && dh == 2) ||
                                     (w == 0 && dw == 0) || (w == W - 1 && dw == 2);
                    if (inv) { s += tp[t]; ++ninv; }
                }
                base2 = basep + (float)(2 * (int)s - 256 * ninv);
            }
            const float res = fmaf(-2.0f, (float)(int)total, base2);
            if (q == 0) o0 = res; else if (q == 1) o1 = res;
            else if (q == 2) o2 = res; else o3 = res;
        }
        reinterpret_cast<float4*>(outrow)[p4] = make_float4(o0, o1, o2, o3);
    }
}

extern "C" void kernel_launch(void* const* d_in, const int* in_sizes, int n_in,
                              void* d_out, int out_size, void* d_ws, size_t ws_size,
                              hipStream_t stream) {
    const float* x = (const float*)d_in[0];
    const float* wt = (const float*)d_in[1];
    const float* bias = (const float*)d_in[2];
    float* out = (float*)d_out;

    uint32_t* px = (uint32_t*)d_ws;                    // 32*58*58*8*4 = 3,444,736 B
    uint32_t* pw = px + (size_t)B * PHW * WORDS;       // + 73,728 B

    pad_zero_kernel<<<(B * 228 * WORDS) / 256, 256, 0, stream>>>(px);
    pack_x_kernel<<<(B * WORDS * (HW / 4)) / 256, 256, 0, stream>>>(x, px);
    pack_w_kernel<<<(C * TAPS * 4 * 64) / 256, 256, 0, stream>>>(wt, pw);

    dim3 grid(HW / 64, B);
    bconv_kernel<<<grid, 256, 0, stream>>>(px, pw, bias, out);
}